// Round 3
// baseline (407.181 us; speedup 1.0000x reference)
//
#include <hip/hip_runtime.h>
#include <hip/hip_bf16.h>

// Problem: B=8, S=1024, E=768, H=12, hd=64, R=16.
// Pipeline:
//   1. cvt q,k,v f32 -> bf16            (ws: qb, 3*M*E)
//   2. W_eff = in_proj_w + lora_b@lora_a -> bf16 (2304x768); cvt out_w -> bf16
//   3. GEMM1: [Q|K|V] = x @ W_eff.T + bias    (z=0,1,2), writes Q*0.125/K as
//      [B,H,S,64] bf16, V transposed [B,H,64,S] bf16
//   4. flash attention per (b,h), O -> [B,S,E] bf16 (aliases qb region)
//   5. GEMM2: out = O @ out_w.T + out_b -> f32 d_out
// ws requirement: ~80.3 MB.

typedef __attribute__((ext_vector_type(4))) float f32x4;
typedef __attribute__((ext_vector_type(8))) short bf16x8;
typedef __attribute__((ext_vector_type(4))) short s16x4;

#define E_DIM 768
#define NB 8
#define SEQ 1024
#define NH 12
#define HD 64
#define M_DIM (NB * SEQ)          // 8192

__device__ __forceinline__ short f2b(float f) {
    union { __hip_bfloat16 h; short s; } u;
    u.h = __float2bfloat16(f);
    return u.s;
}

__device__ __forceinline__ void async_cp16(const void* g, void* l) {
    __builtin_amdgcn_global_load_lds(
        (const __attribute__((address_space(1))) void*)g,
        (__attribute__((address_space(3))) void*)l, 16, 0, 0);
}

// ---------------- conversions ----------------

__global__ void cvt_qkv_kernel(const float* __restrict__ q, const float* __restrict__ k,
                               const float* __restrict__ v, short* __restrict__ dst) {
    const float* src = (blockIdx.y == 0) ? q : (blockIdx.y == 1 ? k : v);
    short* out = dst + (size_t)blockIdx.y * (size_t)(M_DIM * E_DIM);
    size_t i = ((size_t)blockIdx.x * 256 + threadIdx.x) * 8;
    float4 a = *(const float4*)(src + i);
    float4 b = *(const float4*)(src + i + 4);
    bf16x8 o;
    o[0] = f2b(a.x); o[1] = f2b(a.y); o[2] = f2b(a.z); o[3] = f2b(a.w);
    o[4] = f2b(b.x); o[5] = f2b(b.y); o[6] = f2b(b.z); o[7] = f2b(b.w);
    *(bf16x8*)(out + i) = o;
}

// W_eff[r][c] = ipw[r][c] + sum_j lora_b[r][j] * lora_a[j][c], r<2304, c<768
__global__ void weff_kernel(const float* __restrict__ ipw, const float* __restrict__ la,
                            const float* __restrict__ lb, short* __restrict__ W) {
    int idx = blockIdx.x * 256 + threadIdx.x;       // 442368 total
    int r = idx / 192;
    int c = (idx % 192) * 4;
    float4 acc = *(const float4*)(ipw + (size_t)r * E_DIM + c);
    #pragma unroll
    for (int j = 0; j < 16; ++j) {
        float bb = lb[r * 16 + j];
        float4 aa = *(const float4*)(la + j * E_DIM + c);
        acc.x += bb * aa.x; acc.y += bb * aa.y; acc.z += bb * aa.z; acc.w += bb * aa.w;
    }
    s16x4 o; o[0] = f2b(acc.x); o[1] = f2b(acc.y); o[2] = f2b(acc.z); o[3] = f2b(acc.w);
    *(s16x4*)(W + (size_t)r * E_DIM + c) = o;
}

__global__ void cvt_w_kernel(const float* __restrict__ w, short* __restrict__ out) {
    int i = (blockIdx.x * 256 + threadIdx.x) * 4;
    float4 a = *(const float4*)(w + i);
    s16x4 o; o[0] = f2b(a.x); o[1] = f2b(a.y); o[2] = f2b(a.z); o[3] = f2b(a.w);
    *(s16x4*)(out + i) = o;
}

// ---------------- GEMM (C = A @ B^T + bias), 128x128 tile, BK=64 ----------------
// MODE 0: QKV projection epilogue (z = blockIdx.z picks Q/K/V handling)
// MODE 1: final out-proj, f32 output
template <int MODE>
__global__ __launch_bounds__(256) void gemm_bt(
    const short* __restrict__ Aall, const short* __restrict__ Ball,
    const float* __restrict__ biasAll,
    short* __restrict__ Qb, short* __restrict__ Kb, short* __restrict__ Vt,
    float* __restrict__ Cout) {
    __shared__ short sA[128 * 64];
    __shared__ short sB[128 * 64];
    const int z = blockIdx.z;
    const short* Ap = Aall + (size_t)z * (size_t)(M_DIM * E_DIM);
    const short* Bp = Ball + (size_t)z * (size_t)(E_DIM * E_DIM);
    const float* bias = biasAll + z * E_DIM;
    const int tm = blockIdx.x * 128;
    const int tn = blockIdx.y * 128;
    const int t = threadIdx.x;
    const int lane = t & 63, wid = t >> 6;
    const int wr = wid >> 1, wc = wid & 1;
    const int lr = lane & 15, lg = lane >> 4;
    const int srow = lane >> 3;   // 0..7 within a wave's 8-row staging chunk
    const int sgrp = lane & 7;    // 8-elem group within row

    f32x4 acc[4][4] = {};

    for (int k0 = 0; k0 < E_DIM; k0 += 64) {
        // stage A,B tiles: linear LDS dest, inverse-XOR-swizzled global source
        #pragma unroll
        for (int is = 0; is < 4; ++is) {
            const int rbase = is * 32 + wid * 8;
            const int row = rbase + srow;
            const int gsw = (sgrp ^ (row & 7)) << 3;
            async_cp16(Ap + (size_t)(tm + row) * E_DIM + k0 + gsw, &sA[rbase * 64]);
            async_cp16(Bp + (size_t)(tn + row) * E_DIM + k0 + gsw, &sB[rbase * 64]);
        }
        __syncthreads();
        #pragma unroll
        for (int kk = 0; kk < 2; ++kk) {
            bf16x8 af[4], bfr[4];
            const int kg = kk * 4 + lg;
            #pragma unroll
            for (int i = 0; i < 4; ++i) {
                const int row = wr * 64 + i * 16 + lr;
                af[i] = *(const bf16x8*)&sA[row * 64 + ((kg ^ (row & 7)) << 3)];
            }
            #pragma unroll
            for (int j = 0; j < 4; ++j) {
                const int col = wc * 64 + j * 16 + lr;
                bfr[j] = *(const bf16x8*)&sB[col * 64 + ((kg ^ (col & 7)) << 3)];
            }
            #pragma unroll
            for (int i = 0; i < 4; ++i)
                #pragma unroll
                for (int j = 0; j < 4; ++j)
                    acc[i][j] = __builtin_amdgcn_mfma_f32_16x16x32_bf16(
                        af[i], bfr[j], acc[i][j], 0, 0, 0);
        }
        __syncthreads();
    }

    // epilogue: C row m = (lane>>4)*4+r within frag, col n = lane&15
    #pragma unroll
    for (int i = 0; i < 4; ++i) {
        const int m0 = tm + wr * 64 + i * 16 + lg * 4;
        const int b = m0 >> 10;
        const int s0 = m0 & 1023;
        #pragma unroll
        for (int j = 0; j < 4; ++j) {
            const int n = tn + wc * 64 + j * 16 + lr;
            const float bia = bias[n];
            f32x4 a = acc[i][j];
            if (MODE == 1) {
                #pragma unroll
                for (int r = 0; r < 4; ++r)
                    Cout[(size_t)(m0 + r) * E_DIM + n] = a[r] + bia;
            } else {
                const int h = n >> 6, d = n & 63;
                const int bh = b * NH + h;
                if (z == 0) {
                    #pragma unroll
                    for (int r = 0; r < 4; ++r)
                        Qb[((size_t)bh * SEQ + s0 + r) * HD + d] = f2b((a[r] + bia) * 0.125f);
                } else if (z == 1) {
                    #pragma unroll
                    for (int r = 0; r < 4; ++r)
                        Kb[((size_t)bh * SEQ + s0 + r) * HD + d] = f2b(a[r] + bia);
                } else {
                    s16x4 pk;
                    #pragma unroll
                    for (int r = 0; r < 4; ++r) pk[r] = f2b(a[r] + bia);
                    *(s16x4*)&Vt[((size_t)bh * HD + d) * SEQ + s0] = pk;   // V transposed
                }
            }
        }
    }
}

// ---------------- flash attention ----------------
// block: 4 waves; wave owns 16 q rows; iterates 1024 keys in chunks of 64.
// Q pre-scaled by 0.125. K in [B,H,S,64], V in [B,H,64,S] (both bf16).
__global__ __launch_bounds__(256) void attn_kernel(
    const short* __restrict__ Qb, const short* __restrict__ Kb,
    const short* __restrict__ Vt, short* __restrict__ Ob) {
    __shared__ short Plds[4][16 * 80];   // wave-private 16x64 P tile, padded rows (160B)
    const int t = threadIdx.x;
    const int lane = t & 63, wid = t >> 6;
    const int lr = lane & 15, lg = lane >> 4;
    const int bh = blockIdx.y;
    const int q0 = blockIdx.x * 64 + wid * 16;
    const short* Qp = Qb + (size_t)bh * (SEQ * HD);
    const short* Kp = Kb + (size_t)bh * (SEQ * HD);
    const short* Vp = Vt + (size_t)bh * (HD * SEQ);
    short* myP = &Plds[wid][0];

    bf16x8 qf[2];
    qf[0] = *(const bf16x8*)&Qp[(q0 + lr) * HD + lg * 8];
    qf[1] = *(const bf16x8*)&Qp[(q0 + lr) * HD + 32 + lg * 8];

    f32x4 o[4] = {};
    float mr[4] = {-1e30f, -1e30f, -1e30f, -1e30f};
    float lsum[4] = {};

    for (int kb = 0; kb < SEQ; kb += 64) {
        f32x4 sf[4] = {};
        #pragma unroll
        for (int f = 0; f < 4; ++f) {
            const short* Kr = &Kp[(size_t)(kb + f * 16 + lr) * HD + lg * 8];
            bf16x8 kf0 = *(const bf16x8*)Kr;
            bf16x8 kf1 = *(const bf16x8*)(Kr + 32);
            sf[f] = __builtin_amdgcn_mfma_f32_16x16x32_bf16(qf[0], kf0, sf[f], 0, 0, 0);
            sf[f] = __builtin_amdgcn_mfma_f32_16x16x32_bf16(qf[1], kf1, sf[f], 0, 0, 0);
        }
        // per-row max over 64 keys: local frag max + 16-lane butterfly
        float pm[4];
        #pragma unroll
        for (int j = 0; j < 4; ++j)
            pm[j] = fmaxf(fmaxf(sf[0][j], sf[1][j]), fmaxf(sf[2][j], sf[3][j]));
        #pragma unroll
        for (int off = 1; off < 16; off <<= 1)
            #pragma unroll
            for (int j = 0; j < 4; ++j)
                pm[j] = fmaxf(pm[j], __shfl_xor(pm[j], off));
        float sc[4], rs[4] = {};
        #pragma unroll
        for (int j = 0; j < 4; ++j) {
            float mn = fmaxf(mr[j], pm[j]);
            sc[j] = __expf(mr[j] - mn);
            mr[j] = mn;
        }
        #pragma unroll
        for (int f = 0; f < 4; ++f)
            #pragma unroll
            for (int j = 0; j < 4; ++j) {
                float p = __expf(sf[f][j] - mr[j]);
                sf[f][j] = p;
                rs[j] += p;
            }
        #pragma unroll
        for (int off = 1; off < 16; off <<= 1)
            #pragma unroll
            for (int j = 0; j < 4; ++j)
                rs[j] += __shfl_xor(rs[j], off);
        #pragma unroll
        for (int j = 0; j < 4; ++j)
            lsum[j] = lsum[j] * sc[j] + rs[j];
        #pragma unroll
        for (int df = 0; df < 4; ++df)
            #pragma unroll
            for (int j = 0; j < 4; ++j)
                o[df][j] *= sc[j];
        // C-layout P -> LDS (transpose to A-layout for PV)
        #pragma unroll
        for (int f = 0; f < 4; ++f)
            #pragma unroll
            for (int j = 0; j < 4; ++j)
                myP[(lg * 4 + j) * 80 + f * 16 + lr] = f2b(sf[f][j]);
        // PV: wave-private LDS, same-wave RAW handled by compiler lgkmcnt
        #pragma unroll
        for (int kc = 0; kc < 2; ++kc) {
            bf16x8 pf = *(const bf16x8*)&myP[lr * 80 + kc * 32 + lg * 8];
            #pragma unroll
            for (int df = 0; df < 4; ++df) {
                bf16x8 vf = *(const bf16x8*)&Vp[(size_t)(df * 16 + lr) * SEQ + kb + kc * 32 + lg * 8];
                o[df] = __builtin_amdgcn_mfma_f32_16x16x32_bf16(pf, vf, o[df], 0, 0, 0);
            }
        }
    }

    const int b = bh / NH, h = bh % NH;
    #pragma unroll
    for (int j = 0; j < 4; ++j) {
        const float inv = 1.0f / lsum[j];
        const int srow = q0 + lg * 4 + j;
        #pragma unroll
        for (int df = 0; df < 4; ++df)
            Ob[((size_t)b * SEQ + srow) * E_DIM + h * HD + df * 16 + lr] =
                f2b(o[df][j] * inv);
    }
}

// ---------------- launch ----------------

extern "C" void kernel_launch(void* const* d_in, const int* in_sizes, int n_in,
                              void* d_out, int out_size, void* d_ws, size_t ws_size,
                              hipStream_t stream) {
    const float* q   = (const float*)d_in[0];
    const float* k   = (const float*)d_in[1];
    const float* v   = (const float*)d_in[2];
    const float* ipw = (const float*)d_in[3];   // (2304, 768)
    const float* ipb = (const float*)d_in[4];   // (2304,)
    const float* ow  = (const float*)d_in[5];   // (768, 768)
    const float* ob  = (const float*)d_in[6];   // (768,)
    const float* la  = (const float*)d_in[7];   // (16, 768)
    const float* lb  = (const float*)d_in[8];   // (2304, 16)
    float* out = (float*)d_out;

    // workspace layout (shorts); total 80.3 MB
    short* qb   = (short*)d_ws;                                   // 3 * 6291456
    short* weff = qb + (size_t)3 * M_DIM * E_DIM;                 // 1769472
    short* oww  = weff + (size_t)2304 * E_DIM;                    // 589824
    short* Qbf  = oww + (size_t)E_DIM * E_DIM;                    // 6291456
    short* Kbf  = Qbf + (size_t)M_DIM * E_DIM;                    // 6291456
    short* Vtb  = Kbf + (size_t)M_DIM * E_DIM;                    // 6291456
    short* Obf  = qb;  // alias: qb no longer needed after GEMM1

    cvt_qkv_kernel<<<dim3(3072, 3), 256, 0, stream>>>(q, k, v, qb);
    weff_kernel<<<1728, 256, 0, stream>>>(ipw, la, lb, weff);
    cvt_w_kernel<<<576, 256, 0, stream>>>(ow, oww);
    gemm_bt<0><<<dim3(64, 6, 3), 256, 0, stream>>>(qb, weff, ipb, Qbf, Kbf, Vtb, nullptr);
    attn_kernel<<<dim3(16, 96), 256, 0, stream>>>(Qbf, Kbf, Vtb, Obf);
    gemm_bt<1><<<dim3(64, 6, 1), 256, 0, stream>>>(Obf, oww, ob, nullptr, nullptr, nullptr, out);
}

// Round 4
// 294.076 us; speedup vs baseline: 1.3846x; 1.3846x over previous
//
#include <hip/hip_runtime.h>
#include <hip/hip_bf16.h>

// Problem: B=8, S=1024, E=768, H=12, hd=64, R=16.
// Pipeline:
//   1. cvt q,k,v f32 -> bf16            (ws: qb, 3*M*E)
//   2. W_eff = in_proj_w + lora_b@lora_a -> bf16 (2304x768); cvt out_w -> bf16
//   3. GEMM1: [Q|K|V] = x @ W_eff.T + bias    (z=0,1,2), writes Q*0.125/K as
//      [B,H,S,64] bf16, V transposed [B,H,64,S] bf16
//   4. flash attention per (b,h): cooperative LDS-staged K/V (dbuf, XOR-swz),
//      XCD-locality block remap. O -> [B,S,E] bf16 (aliases qb region)
//   5. GEMM2: out = O @ out_w.T + out_b -> f32 d_out
// ws requirement: ~80.3 MB.

typedef __attribute__((ext_vector_type(4))) float f32x4;
typedef __attribute__((ext_vector_type(8))) short bf16x8;
typedef __attribute__((ext_vector_type(4))) short s16x4;

#define E_DIM 768
#define NB 8
#define SEQ 1024
#define NH 12
#define HD 64
#define M_DIM (NB * SEQ)          // 8192

__device__ __forceinline__ short f2b(float f) {
    union { __hip_bfloat16 h; short s; } u;
    u.h = __float2bfloat16(f);
    return u.s;
}

__device__ __forceinline__ void async_cp16(const void* g, void* l) {
    __builtin_amdgcn_global_load_lds(
        (const __attribute__((address_space(1))) void*)g,
        (__attribute__((address_space(3))) void*)l, 16, 0, 0);
}

// ---------------- conversions ----------------

__global__ void cvt_qkv_kernel(const float* __restrict__ q, const float* __restrict__ k,
                               const float* __restrict__ v, short* __restrict__ dst) {
    const float* src = (blockIdx.y == 0) ? q : (blockIdx.y == 1 ? k : v);
    short* out = dst + (size_t)blockIdx.y * (size_t)(M_DIM * E_DIM);
    size_t i = ((size_t)blockIdx.x * 256 + threadIdx.x) * 8;
    float4 a = *(const float4*)(src + i);
    float4 b = *(const float4*)(src + i + 4);
    bf16x8 o;
    o[0] = f2b(a.x); o[1] = f2b(a.y); o[2] = f2b(a.z); o[3] = f2b(a.w);
    o[4] = f2b(b.x); o[5] = f2b(b.y); o[6] = f2b(b.z); o[7] = f2b(b.w);
    *(bf16x8*)(out + i) = o;
}

// W_eff[r][c] = ipw[r][c] + sum_j lora_b[r][j] * lora_a[j][c], r<2304, c<768
__global__ void weff_kernel(const float* __restrict__ ipw, const float* __restrict__ la,
                            const float* __restrict__ lb, short* __restrict__ W) {
    int idx = blockIdx.x * 256 + threadIdx.x;       // 442368 total
    int r = idx / 192;
    int c = (idx % 192) * 4;
    float4 acc = *(const float4*)(ipw + (size_t)r * E_DIM + c);
    #pragma unroll
    for (int j = 0; j < 16; ++j) {
        float bb = lb[r * 16 + j];
        float4 aa = *(const float4*)(la + j * E_DIM + c);
        acc.x += bb * aa.x; acc.y += bb * aa.y; acc.z += bb * aa.z; acc.w += bb * aa.w;
    }
    s16x4 o; o[0] = f2b(acc.x); o[1] = f2b(acc.y); o[2] = f2b(acc.z); o[3] = f2b(acc.w);
    *(s16x4*)(W + (size_t)r * E_DIM + c) = o;
}

__global__ void cvt_w_kernel(const float* __restrict__ w, short* __restrict__ out) {
    int i = (blockIdx.x * 256 + threadIdx.x) * 4;
    float4 a = *(const float4*)(w + i);
    s16x4 o; o[0] = f2b(a.x); o[1] = f2b(a.y); o[2] = f2b(a.z); o[3] = f2b(a.w);
    *(s16x4*)(out + i) = o;
}

// ---------------- GEMM (C = A @ B^T + bias), 128x128 tile, BK=64 ----------------
template <int MODE>
__global__ __launch_bounds__(256) void gemm_bt(
    const short* __restrict__ Aall, const short* __restrict__ Ball,
    const float* __restrict__ biasAll,
    short* __restrict__ Qb, short* __restrict__ Kb, short* __restrict__ Vt,
    float* __restrict__ Cout) {
    __shared__ short sA[128 * 64];
    __shared__ short sB[128 * 64];
    const int z = blockIdx.z;
    const short* Ap = Aall + (size_t)z * (size_t)(M_DIM * E_DIM);
    const short* Bp = Ball + (size_t)z * (size_t)(E_DIM * E_DIM);
    const float* bias = biasAll + z * E_DIM;
    const int tm = blockIdx.x * 128;
    const int tn = blockIdx.y * 128;
    const int t = threadIdx.x;
    const int lane = t & 63, wid = t >> 6;
    const int wr = wid >> 1, wc = wid & 1;
    const int lr = lane & 15, lg = lane >> 4;
    const int srow = lane >> 3;
    const int sgrp = lane & 7;

    f32x4 acc[4][4] = {};

    for (int k0 = 0; k0 < E_DIM; k0 += 64) {
        #pragma unroll
        for (int is = 0; is < 4; ++is) {
            const int rbase = is * 32 + wid * 8;
            const int row = rbase + srow;
            const int gsw = (sgrp ^ (row & 7)) << 3;
            async_cp16(Ap + (size_t)(tm + row) * E_DIM + k0 + gsw, &sA[rbase * 64]);
            async_cp16(Bp + (size_t)(tn + row) * E_DIM + k0 + gsw, &sB[rbase * 64]);
        }
        __syncthreads();
        #pragma unroll
        for (int kk = 0; kk < 2; ++kk) {
            bf16x8 af[4], bfr[4];
            const int kg = kk * 4 + lg;
            #pragma unroll
            for (int i = 0; i < 4; ++i) {
                const int row = wr * 64 + i * 16 + lr;
                af[i] = *(const bf16x8*)&sA[row * 64 + ((kg ^ (row & 7)) << 3)];
            }
            #pragma unroll
            for (int j = 0; j < 4; ++j) {
                const int col = wc * 64 + j * 16 + lr;
                bfr[j] = *(const bf16x8*)&sB[col * 64 + ((kg ^ (col & 7)) << 3)];
            }
            #pragma unroll
            for (int i = 0; i < 4; ++i)
                #pragma unroll
                for (int j = 0; j < 4; ++j)
                    acc[i][j] = __builtin_amdgcn_mfma_f32_16x16x32_bf16(
                        af[i], bfr[j], acc[i][j], 0, 0, 0);
        }
        __syncthreads();
    }

    #pragma unroll
    for (int i = 0; i < 4; ++i) {
        const int m0 = tm + wr * 64 + i * 16 + lg * 4;
        const int b = m0 >> 10;
        const int s0 = m0 & 1023;
        #pragma unroll
        for (int j = 0; j < 4; ++j) {
            const int n = tn + wc * 64 + j * 16 + lr;
            const float bia = bias[n];
            f32x4 a = acc[i][j];
            if (MODE == 1) {
                #pragma unroll
                for (int r = 0; r < 4; ++r)
                    Cout[(size_t)(m0 + r) * E_DIM + n] = a[r] + bia;
            } else {
                const int h = n >> 6, d = n & 63;
                const int bh = b * NH + h;
                if (z == 0) {
                    #pragma unroll
                    for (int r = 0; r < 4; ++r)
                        Qb[((size_t)bh * SEQ + s0 + r) * HD + d] = f2b((a[r] + bia) * 0.125f);
                } else if (z == 1) {
                    #pragma unroll
                    for (int r = 0; r < 4; ++r)
                        Kb[((size_t)bh * SEQ + s0 + r) * HD + d] = f2b(a[r] + bia);
                } else {
                    s16x4 pk;
                    #pragma unroll
                    for (int r = 0; r < 4; ++r) pk[r] = f2b(a[r] + bia);
                    *(s16x4*)&Vt[((size_t)bh * HD + d) * SEQ + s0] = pk;   // V transposed
                }
            }
        }
    }
}

// ---------------- flash attention (cooperative LDS staging) ----------------
// 1-D grid 1536; XCD-locality remap: bh = (p&7)*12 + (p>>3)/16 so each XCD's
// 12 heads' K/V (3MB) fit its 4MB L2. Block = 4 waves, 64 q-rows; wave owns 16.
// K tile [64 k][64 d], V tile [64 d][64 k] staged via global_load_lds (dbuf),
// XOR-swizzled (linear LDS dest + inverse-swz global src, swz on ds_read).
__device__ __forceinline__ void stage_kv(const short* __restrict__ Kp,
                                         const short* __restrict__ Vp, int kb,
                                         short* sKb, short* sVb, int lane, int wid) {
    const int sub = lane >> 3;      // row within 8-row chunk
    const int grp = lane & 7;       // 8-short group within row
    #pragma unroll
    for (int r = 0; r < 2; ++r) {
        const int rbase = r * 32 + wid * 8;
        const int row = rbase + sub;
        const int swz = (grp ^ (row & 7)) << 3;
        async_cp16(Kp + (size_t)(kb + row) * HD + swz, sKb + rbase * HD);
        async_cp16(Vp + (size_t)row * SEQ + kb + swz, sVb + rbase * HD);
    }
}

__global__ __launch_bounds__(256) void attn_kernel(
    const short* __restrict__ Qb, const short* __restrict__ Kb,
    const short* __restrict__ Vt, short* __restrict__ Ob) {
    __shared__ short sK[2][64 * HD];     // 8KB x2
    __shared__ short sV[2][64 * HD];     // 8KB x2
    __shared__ short Plds[4][16 * 80];   // wave-private P, padded rows

    const int t = threadIdx.x;
    const int lane = t & 63, wid = t >> 6;
    const int lr = lane & 15, lg = lane >> 4;

    const int p = blockIdx.x;                    // 0..1535
    const int bh = (p & 7) * 12 + ((p >> 3) >> 4);   // XCD-contiguous heads
    const int qblk = (p >> 3) & 15;
    const int q0 = qblk * 64 + wid * 16;

    const short* Qp = Qb + (size_t)bh * (SEQ * HD);
    const short* Kp = Kb + (size_t)bh * (SEQ * HD);
    const short* Vp = Vt + (size_t)bh * (HD * SEQ);
    short* myP = &Plds[wid][0];

    bf16x8 qf[2];
    qf[0] = *(const bf16x8*)&Qp[(q0 + lr) * HD + lg * 8];
    qf[1] = *(const bf16x8*)&Qp[(q0 + lr) * HD + 32 + lg * 8];

    f32x4 o[4] = {};
    float mr[4] = {-1e30f, -1e30f, -1e30f, -1e30f};
    float lsum[4] = {};

    int cur = 0;
    stage_kv(Kp, Vp, 0, sK[0], sV[0], lane, wid);
    __syncthreads();

    for (int kb = 0; kb < SEQ; kb += 64) {
        if (kb + 64 < SEQ)
            stage_kv(Kp, Vp, kb + 64, sK[cur ^ 1], sV[cur ^ 1], lane, wid);

        // QK^T: sf[f] = Q(16x64) . K^T rows (f*16+lr)
        f32x4 sf[4] = {};
        #pragma unroll
        for (int f = 0; f < 4; ++f) {
            const int row = f * 16 + lr;
            bf16x8 kf0 = *(const bf16x8*)&sK[cur][row * HD + ((lg ^ (row & 7)) << 3)];
            bf16x8 kf1 = *(const bf16x8*)&sK[cur][row * HD + (((lg + 4) ^ (row & 7)) << 3)];
            sf[f] = __builtin_amdgcn_mfma_f32_16x16x32_bf16(qf[0], kf0, sf[f], 0, 0, 0);
            sf[f] = __builtin_amdgcn_mfma_f32_16x16x32_bf16(qf[1], kf1, sf[f], 0, 0, 0);
        }
        // per-row max over 64 keys
        float pm[4];
        #pragma unroll
        for (int j = 0; j < 4; ++j)
            pm[j] = fmaxf(fmaxf(sf[0][j], sf[1][j]), fmaxf(sf[2][j], sf[3][j]));
        #pragma unroll
        for (int off = 1; off < 16; off <<= 1)
            #pragma unroll
            for (int j = 0; j < 4; ++j)
                pm[j] = fmaxf(pm[j], __shfl_xor(pm[j], off));
        float sc[4], rs[4] = {};
        #pragma unroll
        for (int j = 0; j < 4; ++j) {
            float mn = fmaxf(mr[j], pm[j]);
            sc[j] = __expf(mr[j] - mn);
            mr[j] = mn;
        }
        #pragma unroll
        for (int f = 0; f < 4; ++f)
            #pragma unroll
            for (int j = 0; j < 4; ++j) {
                float pv = __expf(sf[f][j] - mr[j]);
                sf[f][j] = pv;
                rs[j] += pv;
            }
        #pragma unroll
        for (int off = 1; off < 16; off <<= 1)
            #pragma unroll
            for (int j = 0; j < 4; ++j)
                rs[j] += __shfl_xor(rs[j], off);
        #pragma unroll
        for (int j = 0; j < 4; ++j)
            lsum[j] = lsum[j] * sc[j] + rs[j];
        #pragma unroll
        for (int df = 0; df < 4; ++df)
            #pragma unroll
            for (int j = 0; j < 4; ++j)
                o[df][j] *= sc[j];
        // P (C-layout) -> LDS transpose to A-layout
        #pragma unroll
        for (int f = 0; f < 4; ++f)
            #pragma unroll
            for (int j = 0; j < 4; ++j)
                myP[(lg * 4 + j) * 80 + f * 16 + lr] = f2b(sf[f][j]);
        // PV from LDS V tile
        #pragma unroll
        for (int kc = 0; kc < 2; ++kc) {
            bf16x8 pf = *(const bf16x8*)&myP[lr * 80 + kc * 32 + lg * 8];
            #pragma unroll
            for (int df = 0; df < 4; ++df) {
                const int row = df * 16 + lr;
                bf16x8 vf = *(const bf16x8*)&sV[cur][row * HD + (((lg + 4 * kc) ^ (row & 7)) << 3)];
                o[df] = __builtin_amdgcn_mfma_f32_16x16x32_bf16(pf, vf, o[df], 0, 0, 0);
            }
        }
        __syncthreads();   // staged tile landed (vmcnt drain) + cur reads done
        cur ^= 1;
    }

    const int b = bh / NH, h = bh % NH;
    #pragma unroll
    for (int j = 0; j < 4; ++j) {
        const float inv = 1.0f / lsum[j];
        const int srow = q0 + lg * 4 + j;
        #pragma unroll
        for (int df = 0; df < 4; ++df)
            Ob[((size_t)b * SEQ + srow) * E_DIM + h * HD + df * 16 + lr] =
                f2b(o[df][j] * inv);
    }
}

// ---------------- launch ----------------

extern "C" void kernel_launch(void* const* d_in, const int* in_sizes, int n_in,
                              void* d_out, int out_size, void* d_ws, size_t ws_size,
                              hipStream_t stream) {
    const float* q   = (const float*)d_in[0];
    const float* k   = (const float*)d_in[1];
    const float* v   = (const float*)d_in[2];
    const float* ipw = (const float*)d_in[3];   // (2304, 768)
    const float* ipb = (const float*)d_in[4];   // (2304,)
    const float* ow  = (const float*)d_in[5];   // (768, 768)
    const float* ob  = (const float*)d_in[6];   // (768,)
    const float* la  = (const float*)d_in[7];   // (16, 768)
    const float* lb  = (const float*)d_in[8];   // (2304, 16)
    float* out = (float*)d_out;

    short* qb   = (short*)d_ws;                                   // 3 * 6291456
    short* weff = qb + (size_t)3 * M_DIM * E_DIM;                 // 1769472
    short* oww  = weff + (size_t)2304 * E_DIM;                    // 589824
    short* Qbf  = oww + (size_t)E_DIM * E_DIM;                    // 6291456
    short* Kbf  = Qbf + (size_t)M_DIM * E_DIM;                    // 6291456
    short* Vtb  = Kbf + (size_t)M_DIM * E_DIM;                    // 6291456
    short* Obf  = qb;  // alias: qb no longer needed after GEMM1

    cvt_qkv_kernel<<<dim3(3072, 3), 256, 0, stream>>>(q, k, v, qb);
    weff_kernel<<<1728, 256, 0, stream>>>(ipw, la, lb, weff);
    cvt_w_kernel<<<576, 256, 0, stream>>>(ow, oww);
    gemm_bt<0><<<dim3(64, 6, 3), 256, 0, stream>>>(qb, weff, ipb, Qbf, Kbf, Vtb, nullptr);
    attn_kernel<<<1536, 256, 0, stream>>>(Qbf, Kbf, Vtb, Obf);
    gemm_bt<1><<<dim3(64, 6, 1), 256, 0, stream>>>(Obf, oww, ob, nullptr, nullptr, nullptr, out);
}

// Round 5
// 257.727 us; speedup vs baseline: 1.5799x; 1.1410x over previous
//
#include <hip/hip_runtime.h>
#include <hip/hip_bf16.h>

// Problem: B=8, S=1024, E=768, H=12, hd=64, R=16.
// Pipeline:
//   1. cvt q,k,v f32 -> bf16            (ws: qb, 3*M*E)
//   2. W_eff = in_proj_w + lora_b@lora_a -> bf16 (2304x768); cvt out_w -> bf16
//   3. GEMM1: [Q|K|V] = x @ W_eff.T + bias    (z=0,1,2), writes Q*0.125/K as
//      [B,H,S,64] bf16, V transposed [B,H,64,S] bf16
//   4. flash attention per (b,h): swapped-QK^T 32x32 MFMA, in-register softmax
//      (cvt_pk + permlane32_swap), defer-max, LDS-staged K/V (dbuf, XOR-swz),
//      XCD-locality remap. O -> [B,S,E] bf16 (aliases qb region)
//   5. GEMM2: out = O @ out_w.T + out_b -> f32 d_out
// ws requirement: ~80.3 MB.

typedef __attribute__((ext_vector_type(4))) float f32x4;
typedef __attribute__((ext_vector_type(16))) float f32x16;
typedef __attribute__((ext_vector_type(8))) short bf16x8;
typedef __attribute__((ext_vector_type(4))) short s16x4;

#define E_DIM 768
#define NB 8
#define SEQ 1024
#define NH 12
#define HD 64
#define M_DIM (NB * SEQ)          // 8192

__device__ __forceinline__ short f2b(float f) {
    union { __hip_bfloat16 h; short s; } u;
    u.h = __float2bfloat16(f);
    return u.s;
}

__device__ __forceinline__ void async_cp16(const void* g, void* l) {
    __builtin_amdgcn_global_load_lds(
        (const __attribute__((address_space(1))) void*)g,
        (__attribute__((address_space(3))) void*)l, 16, 0, 0);
}

// ---------------- conversions ----------------

__global__ void cvt_qkv_kernel(const float* __restrict__ q, const float* __restrict__ k,
                               const float* __restrict__ v, short* __restrict__ dst) {
    const float* src = (blockIdx.y == 0) ? q : (blockIdx.y == 1 ? k : v);
    short* out = dst + (size_t)blockIdx.y * (size_t)(M_DIM * E_DIM);
    size_t i = ((size_t)blockIdx.x * 256 + threadIdx.x) * 8;
    float4 a = *(const float4*)(src + i);
    float4 b = *(const float4*)(src + i + 4);
    bf16x8 o;
    o[0] = f2b(a.x); o[1] = f2b(a.y); o[2] = f2b(a.z); o[3] = f2b(a.w);
    o[4] = f2b(b.x); o[5] = f2b(b.y); o[6] = f2b(b.z); o[7] = f2b(b.w);
    *(bf16x8*)(out + i) = o;
}

// W_eff[r][c] = ipw[r][c] + sum_j lora_b[r][j] * lora_a[j][c], r<2304, c<768
__global__ void weff_kernel(const float* __restrict__ ipw, const float* __restrict__ la,
                            const float* __restrict__ lb, short* __restrict__ W) {
    int idx = blockIdx.x * 256 + threadIdx.x;       // 442368 total
    int r = idx / 192;
    int c = (idx % 192) * 4;
    float4 acc = *(const float4*)(ipw + (size_t)r * E_DIM + c);
    #pragma unroll
    for (int j = 0; j < 16; ++j) {
        float bb = lb[r * 16 + j];
        float4 aa = *(const float4*)(la + j * E_DIM + c);
        acc.x += bb * aa.x; acc.y += bb * aa.y; acc.z += bb * aa.z; acc.w += bb * aa.w;
    }
    s16x4 o; o[0] = f2b(acc.x); o[1] = f2b(acc.y); o[2] = f2b(acc.z); o[3] = f2b(acc.w);
    *(s16x4*)(W + (size_t)r * E_DIM + c) = o;
}

__global__ void cvt_w_kernel(const float* __restrict__ w, short* __restrict__ out) {
    int i = (blockIdx.x * 256 + threadIdx.x) * 4;
    float4 a = *(const float4*)(w + i);
    s16x4 o; o[0] = f2b(a.x); o[1] = f2b(a.y); o[2] = f2b(a.z); o[3] = f2b(a.w);
    *(s16x4*)(out + i) = o;
}

// ---------------- GEMM (C = A @ B^T + bias), 128x128 tile, BK=64 ----------------
template <int MODE>
__global__ __launch_bounds__(256) void gemm_bt(
    const short* __restrict__ Aall, const short* __restrict__ Ball,
    const float* __restrict__ biasAll,
    short* __restrict__ Qb, short* __restrict__ Kb, short* __restrict__ Vt,
    float* __restrict__ Cout) {
    __shared__ short sA[128 * 64];
    __shared__ short sB[128 * 64];
    const int z = blockIdx.z;
    const short* Ap = Aall + (size_t)z * (size_t)(M_DIM * E_DIM);
    const short* Bp = Ball + (size_t)z * (size_t)(E_DIM * E_DIM);
    const float* bias = biasAll + z * E_DIM;
    const int tm = blockIdx.x * 128;
    const int tn = blockIdx.y * 128;
    const int t = threadIdx.x;
    const int lane = t & 63, wid = t >> 6;
    const int wr = wid >> 1, wc = wid & 1;
    const int lr = lane & 15, lg = lane >> 4;
    const int srow = lane >> 3;
    const int sgrp = lane & 7;

    f32x4 acc[4][4] = {};

    for (int k0 = 0; k0 < E_DIM; k0 += 64) {
        #pragma unroll
        for (int is = 0; is < 4; ++is) {
            const int rbase = is * 32 + wid * 8;
            const int row = rbase + srow;
            const int gsw = (sgrp ^ (row & 7)) << 3;
            async_cp16(Ap + (size_t)(tm + row) * E_DIM + k0 + gsw, &sA[rbase * 64]);
            async_cp16(Bp + (size_t)(tn + row) * E_DIM + k0 + gsw, &sB[rbase * 64]);
        }
        __syncthreads();
        #pragma unroll
        for (int kk = 0; kk < 2; ++kk) {
            bf16x8 af[4], bfr[4];
            const int kg = kk * 4 + lg;
            #pragma unroll
            for (int i = 0; i < 4; ++i) {
                const int row = wr * 64 + i * 16 + lr;
                af[i] = *(const bf16x8*)&sA[row * 64 + ((kg ^ (row & 7)) << 3)];
            }
            #pragma unroll
            for (int j = 0; j < 4; ++j) {
                const int col = wc * 64 + j * 16 + lr;
                bfr[j] = *(const bf16x8*)&sB[col * 64 + ((kg ^ (col & 7)) << 3)];
            }
            #pragma unroll
            for (int i = 0; i < 4; ++i)
                #pragma unroll
                for (int j = 0; j < 4; ++j)
                    acc[i][j] = __builtin_amdgcn_mfma_f32_16x16x32_bf16(
                        af[i], bfr[j], acc[i][j], 0, 0, 0);
        }
        __syncthreads();
    }

    #pragma unroll
    for (int i = 0; i < 4; ++i) {
        const int m0 = tm + wr * 64 + i * 16 + lg * 4;
        const int b = m0 >> 10;
        const int s0 = m0 & 1023;
        #pragma unroll
        for (int j = 0; j < 4; ++j) {
            const int n = tn + wc * 64 + j * 16 + lr;
            const float bia = bias[n];
            f32x4 a = acc[i][j];
            if (MODE == 1) {
                #pragma unroll
                for (int r = 0; r < 4; ++r)
                    Cout[(size_t)(m0 + r) * E_DIM + n] = a[r] + bia;
            } else {
                const int h = n >> 6, d = n & 63;
                const int bh = b * NH + h;
                if (z == 0) {
                    #pragma unroll
                    for (int r = 0; r < 4; ++r)
                        Qb[((size_t)bh * SEQ + s0 + r) * HD + d] = f2b((a[r] + bia) * 0.125f);
                } else if (z == 1) {
                    #pragma unroll
                    for (int r = 0; r < 4; ++r)
                        Kb[((size_t)bh * SEQ + s0 + r) * HD + d] = f2b(a[r] + bia);
                } else {
                    s16x4 pk;
                    #pragma unroll
                    for (int r = 0; r < 4; ++r) pk[r] = f2b(a[r] + bia);
                    *(s16x4*)&Vt[((size_t)bh * HD + d) * SEQ + s0] = pk;   // V transposed
                }
            }
        }
    }
}

// ---------------- flash attention (swapped QK^T, in-register softmax) -------
// grid 768 1-D; XCD remap: bh = (p&7)*12 + (p>>3)/8, qblk = (p>>3)&7.
// Block = 4 waves; wave owns 32 q rows (q = q0 + lane&31; hi = lane>>5 splits
// the k/d fragment dims). K tile [32 k][64 d], V tile [64 d][32 k] in LDS,
// double-buffered, XOR-swizzled (linear dest + inverse-swz global source).
// S^T = mfma_32x32x16(K, Q^T): q = lane&31, k = (reg&3)+8*(reg>>2)+4*hi.
// P -> B-frag via v_cvt_pk_bf16_f32 + v_permlane32_swap_b32 (no LDS).
// O^T = mfma(V^T, P^T): per-lane scalar m/l; defer-max THR=8.
__global__ __launch_bounds__(256) void attn_kernel(
    const short* __restrict__ Qb, const short* __restrict__ Kb,
    const short* __restrict__ Vt, short* __restrict__ Ob) {
    __shared__ short sK[2][32 * HD];   // 4KB x2
    __shared__ short sV[2][HD * 32];   // 4KB x2

    const int t = threadIdx.x;
    const int lane = t & 63, wid = t >> 6;
    const int l31 = lane & 31, hi = lane >> 5;

    const int p = blockIdx.x;                        // 0..767
    const int bh = (p & 7) * 12 + ((p >> 3) >> 3);
    const int qblk = (p >> 3) & 7;
    const int q0 = qblk * 128 + wid * 32;

    const short* Qp = Qb + (size_t)bh * (SEQ * HD);
    const short* Kp = Kb + (size_t)bh * (SEQ * HD);
    const short* Vp = Vt + (size_t)bh * (HD * SEQ);

    // Q fragments (B-operand: col=q=l31, k-dim=d=(hi*8+j) per 16-d slice)
    bf16x8 qf[4];
    #pragma unroll
    for (int ds = 0; ds < 4; ++ds)
        qf[ds] = *(const bf16x8*)&Qp[(size_t)(q0 + l31) * HD + ds * 16 + hi * 8];

    f32x16 o0 = {}, o1 = {};
    float mr = -1e30f, lsum = 0.f;

    // staging indices (wave-uniform LDS base + lane-linear 16B slots)
    const int kr = wid * 8 + (lane >> 3), kg = lane & 7;    // K row, 16B group
    const int vr = wid * 16 + (lane >> 2), vg = lane & 3;   // V row, 16B group

    int cur = 0;
    async_cp16(Kp + (size_t)kr * HD + 8 * (kg ^ (kr & 7)), &sK[0][wid * 512]);
    async_cp16(Vp + (size_t)vr * SEQ + 8 * (vg ^ ((vr >> 1) & 3)), &sV[0][wid * 512]);
    __syncthreads();

    for (int kb = 0; kb < SEQ; kb += 32) {
        if (kb + 32 < SEQ) {
            async_cp16(Kp + (size_t)(kb + 32 + kr) * HD + 8 * (kg ^ (kr & 7)),
                       &sK[cur ^ 1][wid * 512]);
            async_cp16(Vp + (size_t)vr * SEQ + (kb + 32) + 8 * (vg ^ ((vr >> 1) & 3)),
                       &sV[cur ^ 1][wid * 512]);
        }
        // QK^T (swapped): st = S^T tile, 4 chained d-slices
        f32x16 st = {};
        #pragma unroll
        for (int ds = 0; ds < 4; ++ds) {
            bf16x8 kf = *(const bf16x8*)&sK[cur][l31 * HD + 8 * ((ds * 2 + hi) ^ (l31 & 7))];
            st = __builtin_amdgcn_mfma_f32_32x32x16_bf16(kf, qf[ds], st, 0, 0, 0);
        }
        // per-q (per-lane) softmax over this 32-key tile
        float tmax = st[0];
        #pragma unroll
        for (int i = 1; i < 16; ++i) tmax = fmaxf(tmax, st[i]);
        tmax = fmaxf(tmax, __shfl_xor(tmax, 32));
        if (!__all(tmax <= mr + 8.0f)) {           // defer-max: rescale rarely
            float mn = fmaxf(mr, tmax);
            float sc = __expf(mr - mn);
            mr = mn;
            lsum *= sc;
            #pragma unroll
            for (int i = 0; i < 16; ++i) { o0[i] *= sc; o1[i] *= sc; }
        }
        float ts = 0.f;
        #pragma unroll
        for (int i = 0; i < 16; ++i) {
            float pv = __expf(st[i] - mr);
            st[i] = pv;
            ts += pv;
        }
        lsum += ts + __shfl_xor(ts, 32);
        // pack P^T B-frags: cvt_pk pairs + permlane32_swap (one per word pair)
        bf16x8 pf[2];
        #pragma unroll
        for (int kc = 0; kc < 2; ++kc) {
            const int b0 = kc * 8;
            unsigned w0, w1, w2, w3;
            asm("v_cvt_pk_bf16_f32 %0, %1, %2" : "=v"(w0) : "v"(st[b0 + 0]), "v"(st[b0 + 1]));
            asm("v_cvt_pk_bf16_f32 %0, %1, %2" : "=v"(w1) : "v"(st[b0 + 2]), "v"(st[b0 + 3]));
            asm("v_cvt_pk_bf16_f32 %0, %1, %2" : "=v"(w2) : "v"(st[b0 + 4]), "v"(st[b0 + 5]));
            asm("v_cvt_pk_bf16_f32 %0, %1, %2" : "=v"(w3) : "v"(st[b0 + 6]), "v"(st[b0 + 7]));
            asm("v_permlane32_swap_b32 %0, %1" : "+v"(w0), "+v"(w2));
            asm("v_permlane32_swap_b32 %0, %1" : "+v"(w1), "+v"(w3));
            union { unsigned u[4]; bf16x8 v; } pk;
            pk.u[0] = w0; pk.u[1] = w1; pk.u[2] = w2; pk.u[3] = w3;
            pf[kc] = pk.v;
        }
        // PV: O^T += V^T . P^T  (A row = d, k-dim = key)
        #pragma unroll
        for (int kc = 0; kc < 2; ++kc) {
            bf16x8 vf0 = *(const bf16x8*)&sV[cur][l31 * 32 +
                             8 * ((kc * 2 + hi) ^ ((l31 >> 1) & 3))];
            o0 = __builtin_amdgcn_mfma_f32_32x32x16_bf16(vf0, pf[kc], o0, 0, 0, 0);
            const int r1 = l31 + 32;
            bf16x8 vf1 = *(const bf16x8*)&sV[cur][r1 * 32 +
                             8 * ((kc * 2 + hi) ^ ((r1 >> 1) & 3))];
            o1 = __builtin_amdgcn_mfma_f32_32x32x16_bf16(vf1, pf[kc], o1, 0, 0, 0);
        }
        __syncthreads();
        cur ^= 1;
    }

    // epilogue: lane holds O[q][*] for q = q0+l31; d = (reg&3)+8*(reg>>2)+4*hi
    const int b = bh / NH, h = bh % NH;
    const float inv = 1.0f / lsum;
    short* orow = Ob + (size_t)(b * SEQ + q0 + l31) * E_DIM + h * HD;
    #pragma unroll
    for (int qi = 0; qi < 4; ++qi) {
        s16x4 pk0, pk1;
        #pragma unroll
        for (int r = 0; r < 4; ++r) {
            pk0[r] = f2b(o0[qi * 4 + r] * inv);
            pk1[r] = f2b(o1[qi * 4 + r] * inv);
        }
        *(s16x4*)&orow[qi * 8 + hi * 4]      = pk0;
        *(s16x4*)&orow[32 + qi * 8 + hi * 4] = pk1;
    }
}

// ---------------- launch ----------------

extern "C" void kernel_launch(void* const* d_in, const int* in_sizes, int n_in,
                              void* d_out, int out_size, void* d_ws, size_t ws_size,
                              hipStream_t stream) {
    const float* q   = (const float*)d_in[0];
    const float* k   = (const float*)d_in[1];
    const float* v   = (const float*)d_in[2];
    const float* ipw = (const float*)d_in[3];   // (2304, 768)
    const float* ipb = (const float*)d_in[4];   // (2304,)
    const float* ow  = (const float*)d_in[5];   // (768, 768)
    const float* ob  = (const float*)d_in[6];   // (768,)
    const float* la  = (const float*)d_in[7];   // (16, 768)
    const float* lb  = (const float*)d_in[8];   // (2304, 16)
    float* out = (float*)d_out;

    short* qb   = (short*)d_ws;                                   // 3 * 6291456
    short* weff = qb + (size_t)3 * M_DIM * E_DIM;                 // 1769472
    short* oww  = weff + (size_t)2304 * E_DIM;                    // 589824
    short* Qbf  = oww + (size_t)E_DIM * E_DIM;                    // 6291456
    short* Kbf  = Qbf + (size_t)M_DIM * E_DIM;                    // 6291456
    short* Vtb  = Kbf + (size_t)M_DIM * E_DIM;                    // 6291456
    short* Obf  = qb;  // alias: qb no longer needed after GEMM1

    cvt_qkv_kernel<<<dim3(3072, 3), 256, 0, stream>>>(q, k, v, qb);
    weff_kernel<<<1728, 256, 0, stream>>>(ipw, la, lb, weff);
    cvt_w_kernel<<<576, 256, 0, stream>>>(ow, oww);
    gemm_bt<0><<<dim3(64, 6, 3), 256, 0, stream>>>(qb, weff, ipb, Qbf, Kbf, Vtb, nullptr);
    attn_kernel<<<768, 256, 0, stream>>>(Qbf, Kbf, Vtb, Obf);
    gemm_bt<1><<<dim3(64, 6, 1), 256, 0, stream>>>(Obf, oww, ob, nullptr, nullptr, nullptr, out);
}